// Round 5
// baseline (418.855 us; speedup 1.0000x reference)
//
#include <hip/hip_runtime.h>

// MultiHeadAttention: B=2, S=4096, D=512, H=8, depth=64. fp32 in/out.
// All matmuls via mfma_f32_16x16x32_f16, fp32 accumulate.
// Pipeline: cvt(q,k,v->f16) + cvt(W->W^T f16) -> 3 proj GEMMs (V written
// pre-transposed [B,H,64,S]) -> flash (64-row Q tiles, 36KB LDS = 4 blk/CU)
// -> output GEMM. Q projection pre-scaled by log2(e) so softmax uses exp2.
#define NH   8
#define DH   64
#define NB   2
#define SEQ  4096
#define DM   512
#define MR   (NB * SEQ)
#define LSTR 72          // LDS row stride in halves (144 B, 16B-aligned)
#define LOG2E 1.44269504089f

using f16x8 = __attribute__((ext_vector_type(8))) _Float16;
using f32x4 = __attribute__((ext_vector_type(4))) float;
#define MFMA16(a, b, c) __builtin_amdgcn_mfma_f32_16x16x32_f16(a, b, c, 0, 0, 0)

// ---------------------------------------------------------------------------
// fp32 -> f16 elementwise for q,k,v. 8 elems/thread. grid 6144 x 256.
// ---------------------------------------------------------------------------
__global__ __launch_bounds__(256) void cvt_qkv(
    const float* __restrict__ q, const float* __restrict__ k,
    const float* __restrict__ v,
    _Float16* __restrict__ Qo, _Float16* __restrict__ Ko, _Float16* __restrict__ Vo)
{
    const size_t PER = (size_t)MR * DM;
    size_t base = ((size_t)blockIdx.x * 256 + threadIdx.x) * 8;
    const int tz = (int)(base / PER);
    const size_t off = base % PER;
    const float* s = (tz == 0) ? q : (tz == 1 ? k : v);
    _Float16* d    = (tz == 0) ? Qo : (tz == 1 ? Ko : Vo);
    float4 a = *(const float4*)(s + off);
    float4 b = *(const float4*)(s + off + 4);
    _Float16 h[8] = { (_Float16)a.x, (_Float16)a.y, (_Float16)a.z, (_Float16)a.w,
                      (_Float16)b.x, (_Float16)b.y, (_Float16)b.z, (_Float16)b.w };
    *(uint4*)(d + off) = *(const uint4*)h;
}

// ---------------------------------------------------------------------------
// W fp32 [k][n] -> Wt f16 [n][k], 4 weights (blockIdx.z). grid (8,8,4) x 256.
// ---------------------------------------------------------------------------
__global__ __launch_bounds__(256) void cvt_w(
    const float* __restrict__ w0, const float* __restrict__ w1,
    const float* __restrict__ w2, const float* __restrict__ w3,
    _Float16* __restrict__ Wt)
{
    __shared__ _Float16 T[64 * LSTR];
    const int z = blockIdx.z;
    const float* W = (z == 0) ? w0 : (z == 1 ? w1 : (z == 2 ? w2 : w3));
    _Float16* out = Wt + (size_t)z * DM * DM;
    const int t = threadIdx.x;
    const int k0 = blockIdx.x * 64, n0 = blockIdx.y * 64;
#pragma unroll
    for (int i = 0; i < 4; ++i) {
        const int kl  = i * 16 + (t >> 4);
        const int nl4 = (t & 15) * 4;
        float4 u = *(const float4*)(W + (size_t)(k0 + kl) * DM + n0 + nl4);
        T[(nl4 + 0) * LSTR + kl] = (_Float16)u.x;
        T[(nl4 + 1) * LSTR + kl] = (_Float16)u.y;
        T[(nl4 + 2) * LSTR + kl] = (_Float16)u.z;
        T[(nl4 + 3) * LSTR + kl] = (_Float16)u.w;
    }
    __syncthreads();
#pragma unroll
    for (int i = 0; i < 2; ++i) {
        const int nl = i * 32 + (t >> 3);
        const int kc = (t & 7) * 8;
        *(uint4*)(out + (size_t)(n0 + nl) * DM + k0 + kc) = *(const uint4*)&T[nl * LSTR + kc];
    }
}

// ---------------------------------------------------------------------------
// GEMM: C[M,512] = X[M,512](f16) @ W(via Wt f16 [n][k]) ; val = scale*(acc+bias).
// OMODE 0: f16 head-split [B,H,S,64] (head == blockIdx.y).
// OMODE 1: f16 TRANSPOSED head-split [B,H,64,S] (for V; LDS-transposed store).
// OMODE 2: fp32 flat [M,512].
// grid (M/128, 8), block 256 (4 waves, wave w owns rows w*32..+32).
// ---------------------------------------------------------------------------
template<int OMODE>
__global__ __launch_bounds__(256) void gemm_mfma(const _Float16* __restrict__ X,
                                                 const _Float16* __restrict__ Wt,
                                                 const float* __restrict__ bias,
                                                 float scale,
                                                 void* __restrict__ outv)
{
    __shared__ _Float16 Xs[128 * LSTR];   // [row][k]
    __shared__ _Float16 Ws[64 * LSTR];    // [n][k]

    const int t = threadIdx.x;
    const int l = t & 63, w = t >> 6;
    const int m = l & 15, g = l >> 4;
    const int row0 = blockIdx.x * 128;
    const int col0 = blockIdx.y * 64;

    f32x4 acc[2][4] = {};

    for (int k0 = 0; k0 < DM; k0 += 64) {
#pragma unroll
        for (int i = 0; i < 4; ++i) {
            const int r  = i * 32 + (t >> 3);
            const int c8 = (t & 7) * 8;
            *(uint4*)&Xs[r * LSTR + c8] =
                *(const uint4*)(X + (size_t)(row0 + r) * DM + k0 + c8);
        }
#pragma unroll
        for (int i = 0; i < 2; ++i) {
            const int n  = i * 32 + (t >> 3);
            const int c8 = (t & 7) * 8;
            *(uint4*)&Ws[n * LSTR + c8] =
                *(const uint4*)(Wt + (size_t)(col0 + n) * DM + k0 + c8);
        }
        __syncthreads();

#pragma unroll
        for (int kk = 0; kk < 2; ++kk) {
            f16x8 a0 = *(const f16x8*)&Xs[(w * 32 + m) * LSTR + kk * 32 + g * 8];
            f16x8 a1 = *(const f16x8*)&Xs[(w * 32 + 16 + m) * LSTR + kk * 32 + g * 8];
#pragma unroll
            for (int ct = 0; ct < 4; ++ct) {
                f16x8 bf = *(const f16x8*)&Ws[(ct * 16 + m) * LSTR + kk * 32 + g * 8];
                acc[0][ct] = MFMA16(a0, bf, acc[0][ct]);
                acc[1][ct] = MFMA16(a1, bf, acc[1][ct]);
            }
        }
        __syncthreads();
    }

    float bv[4];
#pragma unroll
    for (int ct = 0; ct < 4; ++ct) bv[ct] = bias[col0 + ct * 16 + m];

    if (OMODE == 1) {
        // transpose 128x64 tile in LDS (reuse Xs as T[64][136], 16B-aligned rows)
        _Float16* T = Xs;
#pragma unroll
        for (int rt = 0; rt < 2; ++rt)
#pragma unroll
            for (int reg = 0; reg < 4; ++reg) {
                const int s_l = w * 32 + rt * 16 + g * 4 + reg;
#pragma unroll
                for (int ct = 0; ct < 4; ++ct) {
                    const int d = ct * 16 + m;
                    T[d * 136 + s_l] = (_Float16)(scale * (acc[rt][ct][reg] + bv[ct]));
                }
            }
        __syncthreads();
        const int bb = row0 >> 12;
        const int s0 = row0 & (SEQ - 1);
        _Float16* out = (_Float16*)outv;   // [B,H,64,S]
#pragma unroll
        for (int j = 0; j < 4; ++j) {
            const int c = j * 256 + t;
            const int d = c >> 4;
            const int sc = (c & 15) * 8;
            *(uint4*)(out + (((size_t)bb * NH + blockIdx.y) * DH + d) * SEQ + s0 + sc) =
                *(const uint4*)&T[d * 136 + sc];
        }
    } else {
#pragma unroll
        for (int rt = 0; rt < 2; ++rt)
#pragma unroll
            for (int reg = 0; reg < 4; ++reg) {
                const int row = row0 + w * 32 + rt * 16 + g * 4 + reg;
#pragma unroll
                for (int ct = 0; ct < 4; ++ct) {
                    const float val = scale * (acc[rt][ct][reg] + bv[ct]);
                    if (OMODE == 0) {
                        const int bb = row >> 12;
                        const int s  = row & (SEQ - 1);
                        ((_Float16*)outv)[(((size_t)bb * NH + blockIdx.y) * SEQ + s) * DH
                                          + ct * 16 + m] = (_Float16)val;
                    } else {
                        ((float*)outv)[(size_t)row * DM + col0 + ct * 16 + m] = val;
                    }
                }
            }
    }
}

// ---------------------------------------------------------------------------
// Flash attention. Q(=log2e-scaled),K f16 [B*H,S,64]; VT f16 [B*H,64,S];
// mask fp32 [B,1,1,S]; O f16 [B,S,512]. grid (S/64, B*H), block 256
// (4 waves, wave w owns q-rows w*16..+16). LDS 36 KiB -> 4 blocks/CU.
// Logits are in log2 units; p = exp2(s - m). l-reduction deferred to epilogue.
// ---------------------------------------------------------------------------
__global__ __launch_bounds__(256) void flash_mfma(
    const _Float16* __restrict__ Q, const _Float16* __restrict__ K,
    const _Float16* __restrict__ VT, const float* __restrict__ mask,
    _Float16* __restrict__ O)
{
    __shared__ _Float16 Qs [64 * LSTR];  // [qrow][dim]
    __shared__ _Float16 Ks [64 * LSTR];  // [key][dim]
    __shared__ _Float16 VTs[64 * LSTR];  // [dim][key]
    __shared__ _Float16 Ps [64 * LSTR];  // [qrow][key], per-wave 16 rows, swizzled

    const int t = threadIdx.x;
    const int l = t & 63, w = t >> 6;
    const int m = l & 15, g = l >> 4;
    const int bh = blockIdx.y;
    const int b  = bh >> 3;
    const int h  = bh & 7;
    const int q0 = blockIdx.x * 64;

    const _Float16* Qh  = Q  + (size_t)bh * SEQ * DH;
    const _Float16* Kh  = K  + (size_t)bh * SEQ * DH;
    const _Float16* VTh = VT + (size_t)bh * DH * SEQ;
    const float* maskb = mask + (size_t)b * SEQ;

#pragma unroll
    for (int i = 0; i < 2; ++i) {
        const int r  = i * 32 + (t >> 3);
        const int c8 = (t & 7) * 8;
        *(uint4*)&Qs[r * LSTR + c8] = *(const uint4*)(Qh + (size_t)(q0 + r) * DH + c8);
    }

    float m_r[4], l_r[4];
    f32x4 oacc[4] = {};
#pragma unroll
    for (int reg = 0; reg < 4; ++reg) { m_r[reg] = -INFINITY; l_r[reg] = 0.f; }

    for (int t0 = 0; t0 < SEQ; t0 += 64) {
#pragma unroll
        for (int i = 0; i < 2; ++i) {
            const int r  = i * 32 + (t >> 3);
            const int c8 = (t & 7) * 8;
            *(uint4*)&Ks[r * LSTR + c8]  = *(const uint4*)(Kh + (size_t)(t0 + r) * DH + c8);
            *(uint4*)&VTs[r * LSTR + c8] = *(const uint4*)(VTh + (size_t)r * SEQ + t0 + c8);
        }
        __syncthreads();

        // ---- S = Q K^T (log2 units) ----
        f32x4 sacc[4] = {};
#pragma unroll
        for (int kk = 0; kk < 2; ++kk) {
            f16x8 a = *(const f16x8*)&Qs[(w * 16 + m) * LSTR + kk * 32 + g * 8];
#pragma unroll
            for (int ct = 0; ct < 4; ++ct) {
                f16x8 bk = *(const f16x8*)&Ks[(ct * 16 + m) * LSTR + kk * 32 + g * 8];
                sacc[ct] = MFMA16(a, bk, sacc[ct]);
            }
        }

        float mv[4];
#pragma unroll
        for (int ct = 0; ct < 4; ++ct) mv[ct] = maskb[t0 + ct * 16 + m] * (-1e9f * LOG2E);

#pragma unroll
        for (int reg = 0; reg < 4; ++reg) {
            const float s0 = sacc[0][reg] + mv[0];
            const float s1 = sacc[1][reg] + mv[1];
            const float s2 = sacc[2][reg] + mv[2];
            const float s3 = sacc[3][reg] + mv[3];
            float rmax = fmaxf(fmaxf(s0, s1), fmaxf(s2, s3));
            rmax = fmaxf(rmax, __shfl_xor(rmax, 1));
            rmax = fmaxf(rmax, __shfl_xor(rmax, 2));
            rmax = fmaxf(rmax, __shfl_xor(rmax, 4));
            rmax = fmaxf(rmax, __shfl_xor(rmax, 8));
            const float mold = m_r[reg];
            const float mnew = fmaxf(mold, rmax);
            const float alpha = exp2f(mold - mnew);   // first tile: exp2(-inf)=0
            m_r[reg] = mnew;
            const float p0 = exp2f(s0 - mnew);
            const float p1 = exp2f(s1 - mnew);
            const float p2 = exp2f(s2 - mnew);
            const float p3 = exp2f(s3 - mnew);
            l_r[reg] = l_r[reg] * alpha + ((p0 + p1) + (p2 + p3));
#pragma unroll
            for (int nt = 0; nt < 4; ++nt) oacc[nt][reg] *= alpha;

            const int row_l = g * 4 + reg;            // 0..15
            const int swz   = (row_l >> 1) & 7;
            const int base  = (w * 16 + row_l) * LSTR;
            const int mh = m >> 3, ml = m & 7;
            Ps[base + 8 * ((0 + mh) ^ swz) + ml] = (_Float16)p0;
            Ps[base + 8 * ((2 + mh) ^ swz) + ml] = (_Float16)p1;
            Ps[base + 8 * ((4 + mh) ^ swz) + ml] = (_Float16)p2;
            Ps[base + 8 * ((6 + mh) ^ swz) + ml] = (_Float16)p3;
        }
        // Ps is wave-local: no barrier needed before PV.

        // ---- O += P V ----
#pragma unroll
        for (int kk = 0; kk < 2; ++kk) {
            const int pswz = (m >> 1) & 7;
            f16x8 pa = *(const f16x8*)&Ps[(w * 16 + m) * LSTR + 8 * ((kk * 4 + g) ^ pswz)];
#pragma unroll
            for (int nt = 0; nt < 4; ++nt) {
                f16x8 bv = *(const f16x8*)&VTs[(nt * 16 + m) * LSTR + kk * 32 + g * 8];
                oacc[nt] = MFMA16(pa, bv, oacc[nt]);
            }
        }
        __syncthreads();   // Ks/VTs consumed
    }

    // ---- final l reduction (deferred) + store ----
#pragma unroll
    for (int reg = 0; reg < 4; ++reg) {
        float lr = l_r[reg];
        lr += __shfl_xor(lr, 1);
        lr += __shfl_xor(lr, 2);
        lr += __shfl_xor(lr, 4);
        lr += __shfl_xor(lr, 8);
        const float inv = 1.0f / lr;
        const int row = q0 + w * 16 + g * 4 + reg;
#pragma unroll
        for (int nt = 0; nt < 4; ++nt) {
            O[((size_t)b * SEQ + row) * DM + h * DH + nt * 16 + m] =
                (_Float16)(oacc[nt][reg] * inv);
        }
    }
}

extern "C" void kernel_launch(void* const* d_in, const int* in_sizes, int n_in,
                              void* d_out, int out_size, void* d_ws, size_t ws_size,
                              hipStream_t stream) {
    const float* q    = (const float*)d_in[0];
    const float* k    = (const float*)d_in[1];
    const float* v    = (const float*)d_in[2];
    const float* mask = (const float*)d_in[3];
    const float* wq   = (const float*)d_in[4];
    const float* bq   = (const float*)d_in[5];
    const float* wk   = (const float*)d_in[6];
    const float* bk   = (const float*)d_in[7];
    const float* wv   = (const float*)d_in[8];
    const float* bv   = (const float*)d_in[9];
    const float* wo   = (const float*)d_in[10];
    const float* bo   = (const float*)d_in[11];

    // workspace layout (f16, 44 MiB total), with aliasing:
    //   A  : Qin  -> later VT  (V^T [B,H,64,S])
    //   Bq : Kin  -> later Ows (attn out [B,S,512])
    //   C  : Vin
    //   Wt : 4 transposed weights [n][k]
    //   Qws, Kws : projected Q (log2e-scaled), K  [B,H,S,64]
    const size_t P8 = (size_t)MR * DM;
    _Float16* A   = (_Float16*)d_ws;
    _Float16* Bq  = A + P8;
    _Float16* C   = Bq + P8;
    _Float16* Wt  = C + P8;
    _Float16* Qws = Wt + (size_t)4 * DM * DM;
    _Float16* Kws = Qws + P8;

    cvt_qkv<<<dim3(3 * (MR * DM / 8) / 256), 256, 0, stream>>>(q, k, v, A, Bq, C);
    cvt_w<<<dim3(8, 8, 4), 256, 0, stream>>>(wq, wk, wv, wo, Wt);

    const dim3 gg(MR / 128, DM / 64);   // 64 x 8
    gemm_mfma<0><<<gg, 256, 0, stream>>>(A,  Wt,               bq, LOG2E, Qws);
    gemm_mfma<0><<<gg, 256, 0, stream>>>(Bq, Wt + DM * DM,     bk, 1.0f,  Kws);
    gemm_mfma<1><<<gg, 256, 0, stream>>>(C,  Wt + 2 * DM * DM, bv, 1.0f,  A);

    flash_mfma<<<dim3(SEQ / 64, NB * NH), 256, 0, stream>>>(Qws, Kws, A, mask, Bq);

    gemm_mfma<2><<<gg, 256, 0, stream>>>(Bq, Wt + 3 * DM * DM, bo, 1.0f, d_out);
}

// Round 7
// 393.145 us; speedup vs baseline: 1.0654x; 1.0654x over previous
//
#include <hip/hip_runtime.h>

// MultiHeadAttention: B=2, S=4096, D=512, H=8, depth=64. fp32 in/out.
// All matmuls via mfma_f32_16x16x32_f16, fp32 accumulate.
// Flash computes S^T = K Q^T so each lane owns ONE q-row (col=lane&15):
// softmax state is scalar per lane, P^T -> PV B-fragment is a pure register
// shuffle (no LDS round-trip). O^T = V^T P^T. Q pre-scaled by log2(e).
#define NH   8
#define DH   64
#define NB   2
#define SEQ  4096
#define DM   512
#define MR   (NB * SEQ)
#define LSTR 72          // LDS row stride in halves (144 B, 16B-aligned)
#define LOG2E 1.44269504089f

using f16x8 = __attribute__((ext_vector_type(8))) _Float16;
using f32x4 = __attribute__((ext_vector_type(4))) float;
#define MFMA16(a, b, c) __builtin_amdgcn_mfma_f32_16x16x32_f16(a, b, c, 0, 0, 0)

__device__ __forceinline__ unsigned pk_f16(float a, float b) {
    typedef __fp16 fp16v2 __attribute__((ext_vector_type(2)));
    union { fp16v2 h; unsigned u; } c;
    c.h = __builtin_amdgcn_cvt_pkrtz(a, b);   // v_cvt_pkrtz_f16_f32
    return c.u;
}
__device__ __forceinline__ unsigned sel_shfl(unsigned a, unsigned b, int pick, int src) {
    const unsigned va = __shfl(a, src);
    const unsigned vb = __shfl(b, src);
    return pick ? vb : va;
}

// ---------------------------------------------------------------------------
// W fp32 [k][n] -> Wt f16 [n][k], 4 weights (blockIdx.z). grid (8,8,4) x 256.
// ---------------------------------------------------------------------------
__global__ __launch_bounds__(256) void cvt_w(
    const float* __restrict__ w0, const float* __restrict__ w1,
    const float* __restrict__ w2, const float* __restrict__ w3,
    _Float16* __restrict__ Wt)
{
    __shared__ _Float16 T[64 * LSTR];
    const int z = blockIdx.z;
    const float* W = (z == 0) ? w0 : (z == 1 ? w1 : (z == 2 ? w2 : w3));
    _Float16* out = Wt + (size_t)z * DM * DM;
    const int t = threadIdx.x;
    const int k0 = blockIdx.x * 64, n0 = blockIdx.y * 64;
#pragma unroll
    for (int i = 0; i < 4; ++i) {
        const int kl  = i * 16 + (t >> 4);
        const int nl4 = (t & 15) * 4;
        float4 u = *(const float4*)(W + (size_t)(k0 + kl) * DM + n0 + nl4);
        T[(nl4 + 0) * LSTR + kl] = (_Float16)u.x;
        T[(nl4 + 1) * LSTR + kl] = (_Float16)u.y;
        T[(nl4 + 2) * LSTR + kl] = (_Float16)u.z;
        T[(nl4 + 3) * LSTR + kl] = (_Float16)u.w;
    }
    __syncthreads();
#pragma unroll
    for (int i = 0; i < 2; ++i) {
        const int nl = i * 32 + (t >> 3);
        const int kc = (t & 7) * 8;
        *(uint4*)(out + (size_t)(n0 + nl) * DM + k0 + kc) = *(const uint4*)&T[nl * LSTR + kc];
    }
}

// ---------------------------------------------------------------------------
// GEMM: C[M,512] = X[M,512] @ W(via Wt f16 [n][k]); val = scale*(acc+bias).
// XMODE 0: X fp32 global input (convert during staging); 1: X f16 workspace.
// OMODE 0: f16 head-split [B,H,S,64] (head == blockIdx.y).
// OMODE 1: f16 TRANSPOSED head-split [B,H,64,S] (for V).
// OMODE 2: fp32 flat [M,512].
// grid (M/128, 8), block 256 (4 waves).
// ---------------------------------------------------------------------------
template<int XMODE, int OMODE>
__global__ __launch_bounds__(256) void gemm_mfma(const void* __restrict__ Xv,
                                                 const _Float16* __restrict__ Wt,
                                                 const float* __restrict__ bias,
                                                 float scale,
                                                 void* __restrict__ outv)
{
    __shared__ _Float16 Xs[128 * LSTR];   // [row][k]
    __shared__ _Float16 Ws[64 * LSTR];    // [n][k]

    const int t = threadIdx.x;
    const int l = t & 63, w = t >> 6;
    const int m = l & 15, g = l >> 4;
    const int row0 = blockIdx.x * 128;
    const int col0 = blockIdx.y * 64;

    f32x4 acc[2][4] = {};

    for (int k0 = 0; k0 < DM; k0 += 64) {
        if (XMODE == 0) {
            const float* X = (const float*)Xv;
#pragma unroll
            for (int i = 0; i < 8; ++i) {
                const int r  = i * 16 + (t >> 4);
                const int c4 = (t & 15) * 4;
                float4 u = *(const float4*)(X + (size_t)(row0 + r) * DM + k0 + c4);
                uint2 p = make_uint2(pk_f16(u.x, u.y), pk_f16(u.z, u.w));
                *(uint2*)&Xs[r * LSTR + c4] = p;
            }
        } else {
            const _Float16* X = (const _Float16*)Xv;
#pragma unroll
            for (int i = 0; i < 4; ++i) {
                const int r  = i * 32 + (t >> 3);
                const int c8 = (t & 7) * 8;
                *(uint4*)&Xs[r * LSTR + c8] =
                    *(const uint4*)(X + (size_t)(row0 + r) * DM + k0 + c8);
            }
        }
#pragma unroll
        for (int i = 0; i < 2; ++i) {
            const int n  = i * 32 + (t >> 3);
            const int c8 = (t & 7) * 8;
            *(uint4*)&Ws[n * LSTR + c8] =
                *(const uint4*)(Wt + (size_t)(col0 + n) * DM + k0 + c8);
        }
        __syncthreads();

#pragma unroll
        for (int kk = 0; kk < 2; ++kk) {
            f16x8 a0 = *(const f16x8*)&Xs[(w * 32 + m) * LSTR + kk * 32 + g * 8];
            f16x8 a1 = *(const f16x8*)&Xs[(w * 32 + 16 + m) * LSTR + kk * 32 + g * 8];
#pragma unroll
            for (int ct = 0; ct < 4; ++ct) {
                f16x8 bf = *(const f16x8*)&Ws[(ct * 16 + m) * LSTR + kk * 32 + g * 8];
                acc[0][ct] = MFMA16(a0, bf, acc[0][ct]);
                acc[1][ct] = MFMA16(a1, bf, acc[1][ct]);
            }
        }
        __syncthreads();
    }

    float bv[4];
#pragma unroll
    for (int ct = 0; ct < 4; ++ct) bv[ct] = bias[col0 + ct * 16 + m];

    if (OMODE == 1) {
        // transpose 128x64 tile in LDS (reuse Xs as T[64][136])
        _Float16* T = Xs;
#pragma unroll
        for (int rt = 0; rt < 2; ++rt)
#pragma unroll
            for (int reg = 0; reg < 4; ++reg) {
                const int s_l = w * 32 + rt * 16 + g * 4 + reg;
#pragma unroll
                for (int ct = 0; ct < 4; ++ct) {
                    const int d = ct * 16 + m;
                    T[d * 136 + s_l] = (_Float16)(scale * (acc[rt][ct][reg] + bv[ct]));
                }
            }
        __syncthreads();
        const int bb = row0 >> 12;
        const int s0 = row0 & (SEQ - 1);
        _Float16* out = (_Float16*)outv;   // [B,H,64,S]
#pragma unroll
        for (int j = 0; j < 4; ++j) {
            const int c = j * 256 + t;
            const int d = c >> 4;
            const int sc = (c & 15) * 8;
            *(uint4*)(out + (((size_t)bb * NH + blockIdx.y) * DH + d) * SEQ + s0 + sc) =
                *(const uint4*)&T[d * 136 + sc];
        }
    } else {
#pragma unroll
        for (int rt = 0; rt < 2; ++rt)
#pragma unroll
            for (int reg = 0; reg < 4; ++reg) {
                const int row = row0 + w * 32 + rt * 16 + g * 4 + reg;
#pragma unroll
                for (int ct = 0; ct < 4; ++ct) {
                    const float val = scale * (acc[rt][ct][reg] + bv[ct]);
                    if (OMODE == 0) {
                        const int bb = row >> 12;
                        const int s  = row & (SEQ - 1);
                        ((_Float16*)outv)[(((size_t)bb * NH + blockIdx.y) * SEQ + s) * DH
                                          + ct * 16 + m] = (_Float16)val;
                    } else {
                        ((float*)outv)[(size_t)row * DM + col0 + ct * 16 + m] = val;
                    }
                }
            }
    }
}

// ---------------------------------------------------------------------------
// Flash attention, S^T formulation. Q(log2e-scaled),K f16 [B*H,S,64];
// VT f16 [B*H,64,S]; mask fp32 [B,1,1,S]; O f16 [B,S,512].
// grid (S/64, B*H), block 256 (4 waves, wave w owns q-rows w*16 + (lane&15)).
// LDS 27 KiB -> 5 blocks/CU. Softmax state scalar per lane; P^T never
// touches LDS (register shuffle into PV B-fragments).
// ---------------------------------------------------------------------------
__global__ __launch_bounds__(256) void flash_mfma(
    const _Float16* __restrict__ Q, const _Float16* __restrict__ K,
    const _Float16* __restrict__ VT, const float* __restrict__ mask,
    _Float16* __restrict__ O)
{
    __shared__ _Float16 Qs [64 * LSTR];  // [qrow][dim]
    __shared__ _Float16 Ks [64 * LSTR];  // [key][dim]
    __shared__ _Float16 VTs[64 * LSTR];  // [dim][key]

    const int t = threadIdx.x;
    const int l = t & 63, w = t >> 6;
    const int m = l & 15, g = l >> 4;
    const int bh = blockIdx.y;
    const int b  = bh >> 3;
    const int h  = bh & 7;
    const int q0 = blockIdx.x * 64;

    const _Float16* Qh  = Q  + (size_t)bh * SEQ * DH;
    const _Float16* Kh  = K  + (size_t)bh * SEQ * DH;
    const _Float16* VTh = VT + (size_t)bh * DH * SEQ;
    const float* maskb = mask + (size_t)b * SEQ;

#pragma unroll
    for (int i = 0; i < 2; ++i) {
        const int r  = i * 32 + (t >> 3);
        const int c8 = (t & 7) * 8;
        *(uint4*)&Qs[r * LSTR + c8] = *(const uint4*)(Qh + (size_t)(q0 + r) * DH + c8);
    }

    float m_r = -INFINITY, l_r = 0.f;
    f32x4 oacc[4] = {};

    // register-shuffle sources for the P^T -> B-fragment transform
    const int srcA = m + (((g * 2) & 3) << 4);
    const int srcB = m + (((g * 2 + 1) & 3) << 4);
    const int pick = g >> 1;

    for (int t0 = 0; t0 < SEQ; t0 += 64) {
#pragma unroll
        for (int i = 0; i < 2; ++i) {
            const int r  = i * 32 + (t >> 3);
            const int c8 = (t & 7) * 8;
            *(uint4*)&Ks[r * LSTR + c8]  = *(const uint4*)(Kh + (size_t)(t0 + r) * DH + c8);
            *(uint4*)&VTs[r * LSTR + c8] = *(const uint4*)(VTh + (size_t)r * SEQ + t0 + c8);
        }
        __syncthreads();

        // ---- S^T = K Q^T : sacc[kt] rows = keys kt*16 + g*4 + reg, col q = m
        f32x4 sacc[4] = {};
#pragma unroll
        for (int kk = 0; kk < 2; ++kk) {
            f16x8 qf = *(const f16x8*)&Qs[(w * 16 + m) * LSTR + kk * 32 + g * 8];
#pragma unroll
            for (int kt = 0; kt < 4; ++kt) {
                f16x8 kf = *(const f16x8*)&Ks[(kt * 16 + m) * LSTR + kk * 32 + g * 8];
                sacc[kt] = MFMA16(kf, qf, sacc[kt]);
            }
        }

        // ---- mask (per-key, fma) ----
        const float mc = -1e9f * LOG2E;
#pragma unroll
        for (int kt = 0; kt < 4; ++kt) {
            const float4 mk = *(const float4*)&maskb[t0 + kt * 16 + g * 4];
            sacc[kt][0] = fmaf(mk.x, mc, sacc[kt][0]);
            sacc[kt][1] = fmaf(mk.y, mc, sacc[kt][1]);
            sacc[kt][2] = fmaf(mk.z, mc, sacc[kt][2]);
            sacc[kt][3] = fmaf(mk.w, mc, sacc[kt][3]);
        }

        // ---- online softmax, scalar state per lane (one q-row each) ----
        float rmax = -INFINITY;
#pragma unroll
        for (int kt = 0; kt < 4; ++kt) {
            rmax = fmaxf(rmax, fmaxf(fmaxf(sacc[kt][0], sacc[kt][1]),
                                     fmaxf(sacc[kt][2], sacc[kt][3])));
        }
        rmax = fmaxf(rmax, __shfl_xor(rmax, 16));
        rmax = fmaxf(rmax, __shfl_xor(rmax, 32));
        const float mnew  = fmaxf(m_r, rmax);
        const float alpha = exp2f(m_r - mnew);   // first tile: exp2(-inf)=0
        m_r = mnew;

        float psum = 0.f;
        unsigned pkw[4][2];
#pragma unroll
        for (int kt = 0; kt < 4; ++kt) {
            const float p0 = exp2f(sacc[kt][0] - mnew);
            const float p1 = exp2f(sacc[kt][1] - mnew);
            const float p2 = exp2f(sacc[kt][2] - mnew);
            const float p3 = exp2f(sacc[kt][3] - mnew);
            psum += (p0 + p1) + (p2 + p3);
            pkw[kt][0] = pk_f16(p0, p1);
            pkw[kt][1] = pk_f16(p2, p3);
        }
        l_r = l_r * alpha + psum;
#pragma unroll
        for (int dt = 0; dt < 4; ++dt)
#pragma unroll
            for (int r = 0; r < 4; ++r) oacc[dt][r] *= alpha;

        // ---- O^T += V^T P^T ; B-frag assembled by register shuffle ----
#pragma unroll
        for (int kk = 0; kk < 2; ++kk) {
            union { unsigned u[4]; f16x8 h; } pf;
            pf.u[0] = sel_shfl(pkw[2 * kk][0], pkw[2 * kk + 1][0], pick, srcA);
            pf.u[1] = sel_shfl(pkw[2 * kk][1], pkw[2 * kk + 1][1], pick, srcA);
            pf.u[2] = sel_shfl(pkw[2 * kk][0], pkw[2 * kk + 1][0], pick, srcB);
            pf.u[3] = sel_shfl(pkw[2 * kk][1], pkw[2 * kk + 1][1], pick, srcB);
#pragma unroll
            for (int dt = 0; dt < 4; ++dt) {
                f16x8 vf = *(const f16x8*)&VTs[(dt * 16 + m) * LSTR + kk * 32 + g * 8];
                oacc[dt] = MFMA16(vf, pf.h, oacc[dt]);
            }
        }
        __syncthreads();   // Ks/VTs consumed
    }

    // ---- final l reduction + store (O^T: lane q = m, dims dt*16+g*4+reg) ----
    l_r += __shfl_xor(l_r, 16);
    l_r += __shfl_xor(l_r, 32);
    const float inv = 1.0f / l_r;
    const int q = q0 + w * 16 + m;
    _Float16* Orow = O + ((size_t)b * SEQ + q) * DM + h * DH;
#pragma unroll
    for (int dt = 0; dt < 4; ++dt) {
        _Float16 o4[4] = { (_Float16)(oacc[dt][0] * inv), (_Float16)(oacc[dt][1] * inv),
                           (_Float16)(oacc[dt][2] * inv), (_Float16)(oacc[dt][3] * inv) };
        *(uint2*)(Orow + dt * 16 + g * 4) = *(const uint2*)o4;
    }
}

extern "C" void kernel_launch(void* const* d_in, const int* in_sizes, int n_in,
                              void* d_out, int out_size, void* d_ws, size_t ws_size,
                              hipStream_t stream) {
    const float* q    = (const float*)d_in[0];
    const float* k    = (const float*)d_in[1];
    const float* v    = (const float*)d_in[2];
    const float* mask = (const float*)d_in[3];
    const float* wq   = (const float*)d_in[4];
    const float* bq   = (const float*)d_in[5];
    const float* wk   = (const float*)d_in[6];
    const float* bk   = (const float*)d_in[7];
    const float* wv   = (const float*)d_in[8];
    const float* bv   = (const float*)d_in[9];
    const float* wo   = (const float*)d_in[10];
    const float* bo   = (const float*)d_in[11];

    // workspace (f16): Wt 2 MiB; Qws,Kws,VTws,Ows 8 MiB each = 34 MiB
    const size_t P8 = (size_t)MR * DM;
    _Float16* Wt   = (_Float16*)d_ws;
    _Float16* Qws  = Wt + (size_t)4 * DM * DM;
    _Float16* Kws  = Qws + P8;
    _Float16* VTws = Kws + P8;
    _Float16* Ows  = VTws + P8;

    cvt_w<<<dim3(8, 8, 4), 256, 0, stream>>>(wq, wk, wv, wo, Wt);

    const dim3 gg(MR / 128, DM / 64);   // 64 x 8
    gemm_mfma<0, 0><<<gg, 256, 0, stream>>>(q, Wt,               bq, LOG2E, Qws);
    gemm_mfma<0, 0><<<gg, 256, 0, stream>>>(k, Wt + DM * DM,     bk, 1.0f,  Kws);
    gemm_mfma<0, 1><<<gg, 256, 0, stream>>>(v, Wt + 2 * DM * DM, bv, 1.0f,  VTws);

    flash_mfma<<<dim3(SEQ / 64, NB * NH), 256, 0, stream>>>(Qws, Kws, VTws, mask, Ows);

    gemm_mfma<1, 2><<<gg, 256, 0, stream>>>(Ows, Wt + 3 * DM * DM, bo, 1.0f, d_out);
}